// Round 3
// baseline (291.862 us; speedup 1.0000x reference)
//
#include <hip/hip_runtime.h>
#include <cfloat>
#include <cmath>

#define CCH 256   // channels
#define HID 16    // hidden = C / R

typedef float f32x4 __attribute__((ext_vector_type(4)));

// One block per graph (grid-stride). Segment ids are sorted -> contiguous
// ranges found by binary search. Each block:
//   1. streams its segment (float4 x 4 rows in flight), sum+max per channel
//   2. LDS reduce -> avg/max pools
//   3. fused MLP: att = sigmoid((relu(avg@W1+b1)+relu(max@W1+b1))@W2 + 2*b2)
//   4. applies att to its own segment IN REVERSE ORDER so the re-read of x
//      hits L2/L3 (tail of segment was pooled most recently; round-1 profile
//      confirmed FETCH == one x read). Nontemporal stores keep dead output
//      data from evicting the pooled x lines.
__global__ __launch_bounds__(512) void fused_gca_kernel(
    const float* __restrict__ x, const int* __restrict__ seg,
    const int* __restrict__ numg,
    const float* __restrict__ W1, const float* __restrict__ b1,
    const float* __restrict__ W2, const float* __restrict__ b2,
    float* __restrict__ out, int N)
{
    const int G = *numg;
    const int tid = (int)threadIdx.x;
    const int c4  = tid & 63;   // lane: which float4 of the 256-ch row
    const int r   = tid >> 6;   // wave id 0..7 = row group

    __shared__ f32x4 lsum[512];
    __shared__ f32x4 lmax[512];
    __shared__ float pool2[2 * CCH];   // [0:256) avg, [256:512) max
    __shared__ float ht[2 * HID];
    __shared__ float attn[CCH];

    for (int g = (int)blockIdx.x; g < G; g += (int)gridDim.x) {
        // ---- segment bounds: lower_bound(g), lower_bound(g+1) ----
        int lo = 0, hi = N;
        while (lo < hi) { int mid = (lo + hi) >> 1; if (seg[mid] < g) lo = mid + 1; else hi = mid; }
        const int start = lo;
        hi = N;
        while (lo < hi) { int mid = (lo + hi) >> 1; if (seg[mid] <= g) lo = mid + 1; else hi = mid; }
        const int end = lo;
        const int count = end - start;

        // ---- phase 1: pooling stream, 4 rows (4 KB) in flight per wave ----
        f32x4 s = {0.f, 0.f, 0.f, 0.f};
        f32x4 m = {-FLT_MAX, -FLT_MAX, -FLT_MAX, -FLT_MAX};
        const float* xp = x + (size_t)c4 * 4;
        int n = start + r;
        for (; n + 24 < end; n += 32) {
            const f32x4 v0 = *reinterpret_cast<const f32x4*>(xp + (size_t)(n)      * CCH);
            const f32x4 v1 = *reinterpret_cast<const f32x4*>(xp + (size_t)(n + 8)  * CCH);
            const f32x4 v2 = *reinterpret_cast<const f32x4*>(xp + (size_t)(n + 16) * CCH);
            const f32x4 v3 = *reinterpret_cast<const f32x4*>(xp + (size_t)(n + 24) * CCH);
            s += v0;
            m.x = fmaxf(m.x, v0.x); m.y = fmaxf(m.y, v0.y);
            m.z = fmaxf(m.z, v0.z); m.w = fmaxf(m.w, v0.w);
            s += v1;
            m.x = fmaxf(m.x, v1.x); m.y = fmaxf(m.y, v1.y);
            m.z = fmaxf(m.z, v1.z); m.w = fmaxf(m.w, v1.w);
            s += v2;
            m.x = fmaxf(m.x, v2.x); m.y = fmaxf(m.y, v2.y);
            m.z = fmaxf(m.z, v2.z); m.w = fmaxf(m.w, v2.w);
            s += v3;
            m.x = fmaxf(m.x, v3.x); m.y = fmaxf(m.y, v3.y);
            m.z = fmaxf(m.z, v3.z); m.w = fmaxf(m.w, v3.w);
        }
        for (; n < end; n += 8) {
            const f32x4 v0 = *reinterpret_cast<const f32x4*>(xp + (size_t)n * CCH);
            s += v0;
            m.x = fmaxf(m.x, v0.x); m.y = fmaxf(m.y, v0.y);
            m.z = fmaxf(m.z, v0.z); m.w = fmaxf(m.w, v0.w);
        }
        lsum[tid] = s; lmax[tid] = m;
        __syncthreads();

        // ---- phase 2: cross-wave reduce (64 threads own 4 channels each) ----
        if (tid < 64) {
            f32x4 S = lsum[tid];
            f32x4 M = lmax[tid];
            #pragma unroll
            for (int k = 1; k < 8; ++k) {
                const f32x4 S2 = lsum[tid + 64 * k];
                const f32x4 M2 = lmax[tid + 64 * k];
                S += S2;
                M.x = fmaxf(M.x, M2.x); M.y = fmaxf(M.y, M2.y);
                M.z = fmaxf(M.z, M2.z); M.w = fmaxf(M.w, M2.w);
            }
            const float inv = (count > 0) ? 1.0f / (float)count : 0.0f;
            pool2[4 * tid + 0] = S.x * inv;
            pool2[4 * tid + 1] = S.y * inv;
            pool2[4 * tid + 2] = S.z * inv;
            pool2[4 * tid + 3] = S.w * inv;
            pool2[CCH + 4 * tid + 0] = (count > 0) ? M.x : 0.0f;
            pool2[CCH + 4 * tid + 1] = (count > 0) ? M.y : 0.0f;
            pool2[CCH + 4 * tid + 2] = (count > 0) ? M.z : 0.0f;
            pool2[CCH + 4 * tid + 3] = (count > 0) ? M.w : 0.0f;
        }
        __syncthreads();

        // ---- phase 3a: hidden layer, all 512 threads ----
        // 16 threads per (pool,j) pair; partial dot + 16-lane shuffle reduce.
        {
            const int pair = tid >> 4;        // 0..31: (pool = pair>>4, j = pair&15)
            const int sub  = tid & 15;
            const int j    = pair & (HID - 1);
            const float* p = pool2 + (pair >> 4) * CCH;
            float h = 0.f;
            #pragma unroll
            for (int c = sub; c < CCH; c += 16)
                h = fmaf(p[c], W1[c * HID + j], h);
            h += __shfl_xor(h, 8, 64);
            h += __shfl_xor(h, 4, 64);
            h += __shfl_xor(h, 2, 64);
            h += __shfl_xor(h, 1, 64);
            if (sub == 0) ht[pair] = fmaxf(h + b1[j], 0.0f);
        }
        __syncthreads();

        // ---- phase 3b: output layer + sigmoid ----
        if (tid < CCH) {
            float acc = 2.0f * b2[tid];
            #pragma unroll
            for (int j = 0; j < HID; ++j)
                acc = fmaf(ht[j] + ht[HID + j], W2[j * CCH + tid], acc);
            attn[tid] = 1.0f / (1.0f + expf(-acc));
        }
        __syncthreads();

        // ---- phase 4: apply, reverse order for L3 reuse, 4 rows in flight ----
        {
            const f32x4 a4 = *reinterpret_cast<const f32x4*>(attn + c4 * 4);
            const int rem = end - (start + r);
            if (rem > 0) {
                const int rows = (rem + 7) >> 3;   // rows this wave owns
                int k = rows - 1;                  // walk tail -> head
                const float* xq = x   + (size_t)(start + r) * CCH + (size_t)c4 * 4;
                float*       oq = out + (size_t)(start + r) * CCH + (size_t)c4 * 4;
                for (; k >= 3; k -= 4) {
                    const size_t i0 = (size_t)(k)     * (8 * CCH);
                    const size_t i1 = (size_t)(k - 1) * (8 * CCH);
                    const size_t i2 = (size_t)(k - 2) * (8 * CCH);
                    const size_t i3 = (size_t)(k - 3) * (8 * CCH);
                    const f32x4 v0 = *reinterpret_cast<const f32x4*>(xq + i0);
                    const f32x4 v1 = *reinterpret_cast<const f32x4*>(xq + i1);
                    const f32x4 v2 = *reinterpret_cast<const f32x4*>(xq + i2);
                    const f32x4 v3 = *reinterpret_cast<const f32x4*>(xq + i3);
                    __builtin_nontemporal_store(v0 * a4, reinterpret_cast<f32x4*>(oq + i0));
                    __builtin_nontemporal_store(v1 * a4, reinterpret_cast<f32x4*>(oq + i1));
                    __builtin_nontemporal_store(v2 * a4, reinterpret_cast<f32x4*>(oq + i2));
                    __builtin_nontemporal_store(v3 * a4, reinterpret_cast<f32x4*>(oq + i3));
                }
                for (; k >= 0; --k) {
                    const size_t i0 = (size_t)k * (8 * CCH);
                    const f32x4 v0 = *reinterpret_cast<const f32x4*>(xq + i0);
                    __builtin_nontemporal_store(v0 * a4, reinterpret_cast<f32x4*>(oq + i0));
                }
            }
        }
        __syncthreads();  // protect LDS reuse on next grid-stride iteration
    }
}

extern "C" void kernel_launch(void* const* d_in, const int* in_sizes, int n_in,
                              void* d_out, int out_size, void* d_ws, size_t ws_size,
                              hipStream_t stream) {
    const float* x    = (const float*)d_in[0];
    const int*   seg  = (const int*)d_in[1];   // sorted segment ids (int32)
    const int*   numg = (const int*)d_in[2];   // num_graphs scalar (device read)
    const float* W1   = (const float*)d_in[3]; // [C, H]
    const float* b1   = (const float*)d_in[4]; // [H]
    const float* W2   = (const float*)d_in[5]; // [H, C]
    const float* b2   = (const float*)d_in[6]; // [C]
    float* out = (float*)d_out;

    const int N = in_sizes[1];                 // number of nodes

    fused_gca_kernel<<<512, 512, 0, stream>>>(x, seg, numg, W1, b1, W2, b2, out, N);
}